// Round 3
// baseline (488.208 us; speedup 1.0000x reference)
//
#include <hip/hip_runtime.h>

#define B_ 4
#define NH_ 32
#define SQ_ 512
#define HD_ 128
#define MLEN_ 3584
#define KT_ 4096           // MLEN_ + SQ_
#define QB_ 256
#define KB_ 64
#define NTILE_ 64          // KT_ / KB_
#define MEMTILES_ 56       // MLEN_ / KB_

typedef float f32x4 __attribute__((ext_vector_type(4)));
typedef short s16x8 __attribute__((ext_vector_type(8)));

__device__ __forceinline__ f32x4 MFMA16(s16x8 a, s16x8 b, f32x4 c) {
    return __builtin_amdgcn_mfma_f32_16x16x32_bf16(a, b, c, 0, 0, 0);
}

// Barrier that does NOT drain vmcnt: in-flight global loads survive.
// Single asm block so no memory op can be scheduled between wait and barrier.
__device__ __forceinline__ void wg_barrier() {
    asm volatile("s_waitcnt lgkmcnt(0)\n\ts_barrier" ::: "memory");
}

__device__ __forceinline__ s16x8 cvt8(float4 a, float4 b, float sc) {
    union { s16x8 v; __bf16 h[8]; } u;
    u.h[0] = (__bf16)(a.x * sc); u.h[1] = (__bf16)(a.y * sc);
    u.h[2] = (__bf16)(a.z * sc); u.h[3] = (__bf16)(a.w * sc);
    u.h[4] = (__bf16)(b.x * sc); u.h[5] = (__bf16)(b.y * sc);
    u.h[6] = (__bf16)(b.z * sc); u.h[7] = (__bf16)(b.w * sc);
    return u.v;
}

__launch_bounds__(512, 2)
__global__ void attn_kernel(const float* __restrict__ q, const float* __restrict__ k,
                            const float* __restrict__ v, const float* __restrict__ mask,
                            const float* __restrict__ mem, float* __restrict__ ctx)
{
    __shared__ __bf16 Klds[KB_ * HD_];
    __shared__ __bf16 Vt[HD_ * KB_];
    __shared__ __bf16 Plds[8 * 32 * KB_];

    const int tid  = threadIdx.x;
    const int lane = tid & 63;
    const int w    = tid >> 6;
    const int l15  = lane & 15;
    const int l4   = lane >> 4;
    const int xv   = (lane & 7) << 4;

    const int qt   = blockIdx.x >> 7;
    const int pair = blockIdx.x & 127;
    const int b    = pair >> 5;
    const int h    = pair & 31;
    const int q0   = qt * QB_;

    // ---- Q fragments (scale folded in) ----
    const float scale = 0.088388347648318447f;   // 1/sqrt(128)
    s16x8 qf[2][4];
    {
        const float* qbase = q + (((size_t)(b * NH_ + h)) * SQ_ + q0 + w * 32 + l15) * HD_;
        #pragma unroll
        for (int m = 0; m < 2; ++m) {
            #pragma unroll
            for (int kc = 0; kc < 4; ++kc) {
                const float* p = qbase + (size_t)m * 16 * HD_ + kc * 32 + l4 * 8;
                float4 a = *(const float4*)p;
                float4 c = *(const float4*)(p + 4);
                qf[m][kc] = cvt8(a, c, scale);
            }
        }
    }

    f32x4 acc[2][8];
    #pragma unroll
    for (int m = 0; m < 2; ++m)
        #pragma unroll
        for (int n = 0; n < 8; ++n)
            acc[m][n] = (f32x4){0.f, 0.f, 0.f, 0.f};

    float mrun[2][4], lrun[2][4];
    #pragma unroll
    for (int m = 0; m < 2; ++m)
        #pragma unroll
        for (int i = 0; i < 4; ++i) { mrun[m][i] = -3.0e38f; lrun[m][i] = 0.f; }

    const float* maskbase = mask + ((size_t)b * SQ_ + q0 + w * 32 + l4 * 4) * KT_;

    const int krow = tid >> 4,  kcg  = tid & 15;
    const int vhd  = tid & 127, vkvb = tid >> 7;

    float4 kpa[2], kpb[2];
    float  vpre[2][8];

    auto issueKV = [&](int t) {
        const int kv0 = t * KB_;
        const float *srcK, *srcV;
        int rstride;
        if (t < MEMTILES_) {
            const float* mrow = mem + ((size_t)b * MLEN_ + kv0) * (2 * NH_ * HD_) + h * HD_;
            srcK = mrow;
            srcV = mrow + NH_ * HD_;
            rstride = 2 * NH_ * HD_;
        } else {
            size_t off = (((size_t)b * NH_ + h) * SQ_ + (kv0 - MLEN_)) * HD_;
            srcK = k + off;
            srcV = v + off;
            rstride = HD_;
        }
        #pragma unroll
        for (int it = 0; it < 2; ++it) {
            const float* p = srcK + (size_t)(krow + it * 32) * rstride + kcg * 8;
            kpa[it] = *(const float4*)p;
            kpb[it] = *(const float4*)(p + 4);
        }
        #pragma unroll
        for (int it = 0; it < 2; ++it) {
            const float* p = srcV + (size_t)((vkvb + it * 4) * 8) * rstride + vhd;
            #pragma unroll
            for (int j = 0; j < 8; ++j) vpre[it][j] = p[(size_t)j * rstride];
        }
    };
    auto writeKV = [&]() {
        #pragma unroll
        for (int it = 0; it < 2; ++it) {
            int row = krow + it * 32;
            s16x8 vv = cvt8(kpa[it], kpb[it], 1.0f);
            int byte = row * 256 + ((kcg * 16) ^ ((row & 7) << 4));
            *(s16x8*)((char*)Klds + byte) = vv;
        }
        #pragma unroll
        for (int it = 0; it < 2; ++it) {
            int kvb = vkvb + it * 4;
            union { s16x8 v; __bf16 hh[8]; } u;
            #pragma unroll
            for (int j = 0; j < 8; ++j) u.hh[j] = (__bf16)vpre[it][j];
            int byte = vhd * 128 + ((kvb * 16) ^ ((vhd & 7) << 4));
            *(s16x8*)((char*)Vt + byte) = u.v;
        }
    };

    // prologue: stage tile 0, then put tile 1 in flight
    issueKV(0);
    writeKV();
    issueKV(1);

    for (int t = 0; t < NTILE_; ++t) {
        const int kv0 = t * KB_;

        // mask loads for tile t (in flight over barrier + QK phase)
        float mpre[2][4][4];
        #pragma unroll
        for (int m = 0; m < 2; ++m)
            #pragma unroll
            for (int i = 0; i < 4; ++i) {
                const float* mp = maskbase + (size_t)(m * 16 + i) * KT_ + kv0 + l15;
                #pragma unroll
                for (int n = 0; n < 4; ++n) mpre[m][i][n] = mp[n * 16];
            }

        wg_barrier();   // A: LDS writes of tile t visible; KV(t+1) stays in flight

        // ---- S = (Q*scale) @ K^T ----
        f32x4 sa[2][4];
        #pragma unroll
        for (int m = 0; m < 2; ++m)
            #pragma unroll
            for (int n = 0; n < 4; ++n)
                sa[m][n] = (f32x4){0.f, 0.f, 0.f, 0.f};
        #pragma unroll
        for (int n = 0; n < 4; ++n) {
            #pragma unroll
            for (int kc = 0; kc < 4; ++kc) {
                s16x8 kf = *(const s16x8*)((const char*)Klds +
                            (n * 16 + l15) * 256 + (((kc * 4 + l4) * 16) ^ xv));
                sa[0][n] = MFMA16(qf[0][kc], kf, sa[0][n]);
                sa[1][n] = MFMA16(qf[1][kc], kf, sa[1][n]);
            }
        }

        // ---- mask + online softmax (defer-max, THR=8) ----
        #pragma unroll
        for (int m = 0; m < 2; ++m) {
            #pragma unroll
            for (int i = 0; i < 4; ++i) {
                sa[m][0][i] = fmaf(mpre[m][i][0], sa[m][0][i] + 10000.f, -10000.f);
                sa[m][1][i] = fmaf(mpre[m][i][1], sa[m][1][i] + 10000.f, -10000.f);
                sa[m][2][i] = fmaf(mpre[m][i][2], sa[m][2][i] + 10000.f, -10000.f);
                sa[m][3][i] = fmaf(mpre[m][i][3], sa[m][3][i] + 10000.f, -10000.f);

                float rm = fmaxf(fmaxf(sa[m][0][i], sa[m][1][i]),
                                 fmaxf(sa[m][2][i], sa[m][3][i]));
                rm = fmaxf(rm, __shfl_xor(rm, 1));
                rm = fmaxf(rm, __shfl_xor(rm, 2));
                rm = fmaxf(rm, __shfl_xor(rm, 4));
                rm = fmaxf(rm, __shfl_xor(rm, 8));

                if (!__all(rm <= mrun[m][i] + 8.f)) {
                    float om = mrun[m][i];
                    float nm = fmaxf(om, rm);
                    float al = __expf(om - nm);
                    mrun[m][i] = nm;
                    lrun[m][i] *= al;
                    #pragma unroll
                    for (int nn = 0; nn < 8; ++nn) acc[m][nn][i] *= al;
                }
                float mcur = mrun[m][i];

                float rs = 0.f;
                #pragma unroll
                for (int n = 0; n < 4; ++n) {
                    float pe = __expf(sa[m][n][i] - mcur);
                    sa[m][n][i] = pe;
                    rs += pe;
                }
                rs += __shfl_xor(rs, 1);
                rs += __shfl_xor(rs, 2);
                rs += __shfl_xor(rs, 4);
                rs += __shfl_xor(rs, 8);
                lrun[m][i] += rs;
            }
        }

        // ---- P -> bf16 -> per-wave LDS (swizzled) ----
        __bf16* pw = &Plds[w * (32 * KB_)];
        #pragma unroll
        for (int m = 0; m < 2; ++m)
            #pragma unroll
            for (int n = 0; n < 4; ++n)
                #pragma unroll
                for (int i = 0; i < 4; ++i) {
                    int row = m * 16 + l4 * 4 + i;
                    int col = n * 16 + l15;
                    int byte = row * 128 + ((col * 2) ^ ((row & 7) << 4));
                    *(__bf16*)((char*)pw + byte) = (__bf16)sa[m][n][i];
                }

        // ---- O += P @ V ----
        s16x8 pf[2][2];
        #pragma unroll
        for (int m = 0; m < 2; ++m)
            #pragma unroll
            for (int kt = 0; kt < 2; ++kt)
                pf[m][kt] = *(const s16x8*)((const char*)pw +
                              (m * 16 + l15) * 128 + ((kt * 64 + l4 * 16) ^ xv));
        #pragma unroll
        for (int nn = 0; nn < 8; ++nn) {
            s16x8 vf0 = *(const s16x8*)((const char*)Vt +
                          (nn * 16 + l15) * 128 + ((l4 * 16) ^ xv));
            s16x8 vf1 = *(const s16x8*)((const char*)Vt +
                          (nn * 16 + l15) * 128 + ((64 + l4 * 16) ^ xv));
            #pragma unroll
            for (int m = 0; m < 2; ++m) {
                acc[m][nn] = MFMA16(pf[m][0], vf0, acc[m][nn]);
                acc[m][nn] = MFMA16(pf[m][1], vf1, acc[m][nn]);
            }
        }

        wg_barrier();   // B: all waves' LDS reads of tile t retired

        if (t + 1 < NTILE_) writeKV();      // vmcnt waits happen HERE (after compute)
        if (t + 2 < NTILE_) issueKV(t + 2); // next prefetch in flight
    }

    // ---- epilogue: normalize + store f32 ----
    float* obase = ctx + (((size_t)(b * NH_ + h)) * SQ_ + q0 + w * 32 + l4 * 4) * HD_ + l15;
    #pragma unroll
    for (int m = 0; m < 2; ++m)
        #pragma unroll
        for (int i = 0; i < 4; ++i) {
            float inv = 1.f / lrun[m][i];
            #pragma unroll
            for (int nn = 0; nn < 8; ++nn)
                obase[(size_t)(m * 16 + i) * HD_ + nn * 16] = acc[m][nn][i] * inv;
        }
}

// cache_kv: out[b][s][part][h][d] = (part ? v : k)[b][h][s][d]
__global__ void cachekv_kernel(const float* __restrict__ k, const float* __restrict__ v,
                               float* __restrict__ out)
{
    size_t i = ((size_t)blockIdx.x * 256 + threadIdx.x) * 4;
    unsigned f = (unsigned)i;
    unsigned d    = f & 127;
    unsigned hh   = (f >> 7) & 31;
    unsigned part = (f >> 12) & 1;
    unsigned s    = (f >> 13) & 511;
    unsigned bb   = f >> 22;
    const float* src = (part ? v : k) + (((size_t)(bb * 32u + hh)) * 512u + s) * 128u + d;
    *(float4*)(out + i) = *(const float4*)src;
}

extern "C" void kernel_launch(void* const* d_in, const int* in_sizes, int n_in,
                              void* d_out, int out_size, void* d_ws, size_t ws_size,
                              hipStream_t stream) {
    const float* q    = (const float*)d_in[0];
    const float* k    = (const float*)d_in[1];
    const float* v    = (const float*)d_in[2];
    const float* mask = (const float*)d_in[3];
    const float* mem  = (const float*)d_in[4];
    float* out = (float*)d_out;

    attn_kernel<<<dim3(B_ * NH_ * (SQ_ / QB_)), dim3(512), 0, stream>>>(q, k, v, mask, mem, out);

    const int ctx_elems = B_ * NH_ * SQ_ * HD_;                 // 8388608
    const int ckv_elems = B_ * SQ_ * 2 * NH_ * HD_;             // 16777216
    cachekv_kernel<<<dim3(ckv_elems / 4 / 256), dim3(256), 0, stream>>>(k, v, out + ctx_elems);
    (void)in_sizes; (void)n_in; (void)out_size; (void)d_ws; (void)ws_size;
}

// Round 4
// 340.006 us; speedup vs baseline: 1.4359x; 1.4359x over previous
//
#include <hip/hip_runtime.h>

#define B_ 4
#define NH_ 32
#define SQ_ 512
#define HD_ 128
#define MLEN_ 3584
#define KT_ 4096           // MLEN_ + SQ_
#define QB_ 128
#define KB_ 64
#define NTILE_ 64          // KT_ / KB_
#define MEMTILES_ 56       // MLEN_ / KB_

typedef float f32x4 __attribute__((ext_vector_type(4)));
typedef short s16x8 __attribute__((ext_vector_type(8)));

__device__ __forceinline__ f32x4 MFMA16(s16x8 a, s16x8 b, f32x4 c) {
    return __builtin_amdgcn_mfma_f32_16x16x32_bf16(a, b, c, 0, 0, 0);
}

__device__ __forceinline__ s16x8 cvt8(float4 a, float4 b, float sc) {
    union { s16x8 v; __bf16 h[8]; } u;
    u.h[0] = (__bf16)(a.x * sc); u.h[1] = (__bf16)(a.y * sc);
    u.h[2] = (__bf16)(a.z * sc); u.h[3] = (__bf16)(a.w * sc);
    u.h[4] = (__bf16)(b.x * sc); u.h[5] = (__bf16)(b.y * sc);
    u.h[6] = (__bf16)(b.z * sc); u.h[7] = (__bf16)(b.w * sc);
    return u.v;
}

// 4 waves, 48KB LDS -> 2 independent blocks/CU (the R1..R3 structure had 1
// lockstep 8-wave block/CU: every barrier stalled the whole CU).
__launch_bounds__(256, 2)
__global__ void attn_kernel(const float* __restrict__ q, const float* __restrict__ k,
                            const float* __restrict__ v, const float* __restrict__ mask,
                            const float* __restrict__ mem, float* __restrict__ ctx)
{
    __shared__ __bf16 Klds[KB_ * HD_];        // 16 KB, swizzled rows
    __shared__ __bf16 Vt[HD_ * KB_];          // 16 KB, transposed + swizzled
    __shared__ __bf16 Plds[4 * 32 * KB_];     // 16 KB, per-wave P

    const int tid  = threadIdx.x;
    const int lane = tid & 63;
    const int w    = tid >> 6;                // 0..3
    const int l15  = lane & 15;
    const int l4   = lane >> 4;
    const int xv   = (lane & 7) << 4;

    // grid = 512: qt in 0..3, same head's 4 q-tiles are bid%128-equal -> same XCD
    const int qt   = blockIdx.x >> 7;
    const int pair = blockIdx.x & 127;
    const int b    = pair >> 5;
    const int h    = pair & 31;
    const int q0   = qt * QB_;

    // ---- Q fragments (scale folded in); wave w owns rows q0+w*32 .. +31 ----
    const float scale = 0.088388347648318447f;   // 1/sqrt(128)
    s16x8 qf[2][4];
    {
        const float* qbase = q + (((size_t)(b * NH_ + h)) * SQ_ + q0 + w * 32 + l15) * HD_;
        #pragma unroll
        for (int m = 0; m < 2; ++m) {
            #pragma unroll
            for (int kc = 0; kc < 4; ++kc) {
                const float* p = qbase + (size_t)m * 16 * HD_ + kc * 32 + l4 * 8;
                float4 a = *(const float4*)p;
                float4 c = *(const float4*)(p + 4);
                qf[m][kc] = cvt8(a, c, scale);
            }
        }
    }

    f32x4 acc[2][8];
    #pragma unroll
    for (int m = 0; m < 2; ++m)
        #pragma unroll
        for (int n = 0; n < 8; ++n)
            acc[m][n] = (f32x4){0.f, 0.f, 0.f, 0.f};

    float mrun[2][4], lrun[2][4];
    #pragma unroll
    for (int m = 0; m < 2; ++m)
        #pragma unroll
        for (int i = 0; i < 4; ++i) { mrun[m][i] = -3.0e38f; lrun[m][i] = 0.f; }

    const float* maskbase = mask + ((size_t)b * SQ_ + q0 + w * 32 + l4 * 4) * KT_;

    for (int t = 0; t < NTILE_; ++t) {
        const int kv0 = t * KB_;
        const float *srcK, *srcV;
        int rstride;
        if (t < MEMTILES_) {
            const float* mrow = mem + ((size_t)b * MLEN_ + kv0) * (2 * NH_ * HD_) + h * HD_;
            srcK = mrow;
            srcV = mrow + NH_ * HD_;
            rstride = 2 * NH_ * HD_;
        } else {
            size_t off = (((size_t)b * NH_ + h) * SQ_ + (kv0 - MLEN_)) * HD_;
            srcK = k + off;
            srcV = v + off;
            rstride = HD_;
        }

        __syncthreads();   // previous tile's LDS reads complete

        // ---- K stage: 1024 x 16B chunks over 256 threads ----
        #pragma unroll
        for (int it = 0; it < 4; ++it) {
            int idx = tid + it * 256;
            int row = idx >> 4, cg = idx & 15;
            const float* p = srcK + (size_t)row * rstride + cg * 8;
            float4 a = *(const float4*)p;
            float4 c = *(const float4*)(p + 4);
            s16x8 vv = cvt8(a, c, 1.0f);
            int byte = row * 256 + ((cg * 16) ^ ((row & 7) << 4));
            *(s16x8*)((char*)Klds + byte) = vv;
        }
        // ---- V stage (transposed) ----
        #pragma unroll
        for (int it = 0; it < 4; ++it) {
            int idx = tid + it * 256;
            int hd = idx & 127, kvb = idx >> 7;
            const float* p = srcV + (size_t)(kvb * 8) * rstride + hd;
            union { s16x8 v; __bf16 hh[8]; } u;
            #pragma unroll
            for (int j = 0; j < 8; ++j) u.hh[j] = (__bf16)p[(size_t)j * rstride];
            int byte = hd * 128 + ((kvb * 16) ^ ((hd & 7) << 4));
            *(s16x8*)((char*)Vt + byte) = u.v;
        }

        // ---- mask loads for this tile (drain at the same barrier as the stage) ----
        float mpre[2][4][4];
        #pragma unroll
        for (int m = 0; m < 2; ++m)
            #pragma unroll
            for (int i = 0; i < 4; ++i) {
                const float* mp = maskbase + (size_t)(m * 16 + i) * KT_ + kv0 + l15;
                #pragma unroll
                for (int n = 0; n < 4; ++n) mpre[m][i][n] = mp[n * 16];
            }

        __syncthreads();   // tile staged

        // ---- S = (Q*scale) @ K^T ----
        f32x4 sa[2][4];
        #pragma unroll
        for (int m = 0; m < 2; ++m)
            #pragma unroll
            for (int n = 0; n < 4; ++n)
                sa[m][n] = (f32x4){0.f, 0.f, 0.f, 0.f};
        #pragma unroll
        for (int n = 0; n < 4; ++n) {
            #pragma unroll
            for (int kc = 0; kc < 4; ++kc) {
                s16x8 kf = *(const s16x8*)((const char*)Klds +
                            (n * 16 + l15) * 256 + (((kc * 4 + l4) * 16) ^ xv));
                sa[0][n] = MFMA16(qf[0][kc], kf, sa[0][n]);
                sa[1][n] = MFMA16(qf[1][kc], kf, sa[1][n]);
            }
        }

        // ---- mask + online softmax (rows: m*16 + l4*4 + i; cols: n*16 + l15) ----
        #pragma unroll
        for (int m = 0; m < 2; ++m) {
            #pragma unroll
            for (int i = 0; i < 4; ++i) {
                sa[m][0][i] = fmaf(mpre[m][i][0], sa[m][0][i] + 10000.f, -10000.f);
                sa[m][1][i] = fmaf(mpre[m][i][1], sa[m][1][i] + 10000.f, -10000.f);
                sa[m][2][i] = fmaf(mpre[m][i][2], sa[m][2][i] + 10000.f, -10000.f);
                sa[m][3][i] = fmaf(mpre[m][i][3], sa[m][3][i] + 10000.f, -10000.f);

                float rm = fmaxf(fmaxf(sa[m][0][i], sa[m][1][i]),
                                 fmaxf(sa[m][2][i], sa[m][3][i]));
                rm = fmaxf(rm, __shfl_xor(rm, 1));
                rm = fmaxf(rm, __shfl_xor(rm, 2));
                rm = fmaxf(rm, __shfl_xor(rm, 4));
                rm = fmaxf(rm, __shfl_xor(rm, 8));

                float om = mrun[m][i];
                float nm = fmaxf(om, rm);
                float al = __expf(om - nm);
                mrun[m][i] = nm;

                float rs = 0.f;
                #pragma unroll
                for (int n = 0; n < 4; ++n) {
                    float pe = __expf(sa[m][n][i] - nm);
                    sa[m][n][i] = pe;
                    rs += pe;
                }
                rs += __shfl_xor(rs, 1);
                rs += __shfl_xor(rs, 2);
                rs += __shfl_xor(rs, 4);
                rs += __shfl_xor(rs, 8);
                lrun[m][i] = lrun[m][i] * al + rs;

                #pragma unroll
                for (int nn = 0; nn < 8; ++nn) acc[m][nn][i] *= al;
            }
        }

        // ---- P -> bf16 -> per-wave LDS (swizzled) ----
        __bf16* pw = &Plds[w * (32 * KB_)];
        #pragma unroll
        for (int m = 0; m < 2; ++m)
            #pragma unroll
            for (int n = 0; n < 4; ++n)
                #pragma unroll
                for (int i = 0; i < 4; ++i) {
                    int row = m * 16 + l4 * 4 + i;
                    int col = n * 16 + l15;
                    int byte = row * 128 + ((col * 2) ^ ((row & 7) << 4));
                    *(__bf16*)((char*)pw + byte) = (__bf16)sa[m][n][i];
                }

        // ---- O += P @ V ----
        s16x8 pf[2][2];
        #pragma unroll
        for (int m = 0; m < 2; ++m)
            #pragma unroll
            for (int kt = 0; kt < 2; ++kt)
                pf[m][kt] = *(const s16x8*)((const char*)pw +
                              (m * 16 + l15) * 128 + ((kt * 64 + l4 * 16) ^ xv));
        #pragma unroll
        for (int nn = 0; nn < 8; ++nn) {
            s16x8 vf0 = *(const s16x8*)((const char*)Vt +
                          (nn * 16 + l15) * 128 + ((l4 * 16) ^ xv));
            s16x8 vf1 = *(const s16x8*)((const char*)Vt +
                          (nn * 16 + l15) * 128 + ((64 + l4 * 16) ^ xv));
            #pragma unroll
            for (int m = 0; m < 2; ++m) {
                acc[m][nn] = MFMA16(pf[m][0], vf0, acc[m][nn]);
                acc[m][nn] = MFMA16(pf[m][1], vf1, acc[m][nn]);
            }
        }
    }

    // ---- epilogue: normalize + store f32 ----
    float* obase = ctx + (((size_t)(b * NH_ + h)) * SQ_ + q0 + w * 32 + l4 * 4) * HD_ + l15;
    #pragma unroll
    for (int m = 0; m < 2; ++m)
        #pragma unroll
        for (int i = 0; i < 4; ++i) {
            float inv = 1.f / lrun[m][i];
            #pragma unroll
            for (int nn = 0; nn < 8; ++nn)
                obase[(size_t)(m * 16 + i) * HD_ + nn * 16] = acc[m][nn][i] * inv;
        }
}

// cache_kv: out[b][s][part][h][d] = (part ? v : k)[b][h][s][d]
__global__ void cachekv_kernel(const float* __restrict__ k, const float* __restrict__ v,
                               float* __restrict__ out)
{
    size_t i = ((size_t)blockIdx.x * 256 + threadIdx.x) * 4;
    unsigned f = (unsigned)i;
    unsigned d    = f & 127;
    unsigned hh   = (f >> 7) & 31;
    unsigned part = (f >> 12) & 1;
    unsigned s    = (f >> 13) & 511;
    unsigned bb   = f >> 22;
    const float* src = (part ? v : k) + (((size_t)(bb * 32u + hh)) * 512u + s) * 128u + d;
    *(float4*)(out + i) = *(const float4*)src;
}

extern "C" void kernel_launch(void* const* d_in, const int* in_sizes, int n_in,
                              void* d_out, int out_size, void* d_ws, size_t ws_size,
                              hipStream_t stream) {
    const float* q    = (const float*)d_in[0];
    const float* k    = (const float*)d_in[1];
    const float* v    = (const float*)d_in[2];
    const float* mask = (const float*)d_in[3];
    const float* mem  = (const float*)d_in[4];
    float* out = (float*)d_out;

    attn_kernel<<<dim3(B_ * NH_ * (SQ_ / QB_)), dim3(256), 0, stream>>>(q, k, v, mask, mem, out);

    const int ctx_elems = B_ * NH_ * SQ_ * HD_;                 // 8388608
    const int ckv_elems = B_ * SQ_ * 2 * NH_ * HD_;             // 16777216
    cachekv_kernel<<<dim3(ckv_elems / 4 / 256), dim3(256), 0, stream>>>(k, v, out + ctx_elems);
    (void)in_sizes; (void)n_in; (void)out_size; (void)d_ws; (void)ws_size;
}